// Round 3
// baseline (635.860 us; speedup 1.0000x reference)
//
#include <hip/hip_runtime.h>
#include <hip/hip_bf16.h>
#include <math.h>

// Problem constants (fixed by reference)
#define NTOK 8192     // B*S
#define HD   4096     // H
#define NE   8        // experts
#define NA   64       // adapter dim
#define EAD  512      // NE*NA

typedef __attribute__((ext_vector_type(8))) short  short8;   // 8 bf16 (MFMA frag)
typedef __attribute__((ext_vector_type(4))) float  f32x4;    // MFMA acc

__device__ __forceinline__ unsigned short f2bf(float f) {
  unsigned u = __float_as_uint(f);
  u += 0x7fffu + ((u >> 16) & 1u);   // round-to-nearest-even
  return (unsigned short)(u >> 16);
}

__device__ __forceinline__ float gelu_exact(float v) {
  return 0.5f * v * (1.0f + erff(v * 0.70710678118654752f));
}

// ---------------- K0: weight convert/transpose to bf16 ----------------
// Bd[ea][h]   = Wd[e][a][h]        (identity reinterpret, [512][4096])
// Bu[hcol][ea] = Wu[e][hcol][a]    (transpose within expert, [4096][512])
__global__ __launch_bounds__(256) void k0_convert(const float* __restrict__ Wd,
                                                  const float* __restrict__ Wu,
                                                  unsigned short* __restrict__ Bd,
                                                  unsigned short* __restrict__ Bu) {
  int idx = blockIdx.x * 256 + threadIdx.x;
  const int M = EAD * HD;  // 2,097,152
  if (idx < M) {
    Bd[idx] = f2bf(Wd[idx]);
  } else {
    int j = idx - M;               // j = hcol*512 + e*64 + a
    int a = j & 63;
    int e = (j >> 6) & 7;
    int hcol = j >> 9;
    Bu[j] = f2bf(Wu[((size_t)e * HD + hcol) * NA + a]);
  }
}

// ---------------- K1: router logits (f32) + top-2 softmax -> coef ----------------
// One wave handles 4 tokens; block = 4 waves = 16 tokens.
__global__ __launch_bounds__(256) void k1_router(const float* __restrict__ rh,
                                                 const float* __restrict__ Wr,
                                                 float* __restrict__ coef,
                                                 float* __restrict__ logits) {
  const int t = threadIdx.x;
  const int wave = t >> 6, l = t & 63;
  const int tok0 = blockIdx.x * 16 + wave * 4;

  float acc[4][8];
#pragma unroll
  for (int i = 0; i < 4; ++i)
#pragma unroll
    for (int e = 0; e < 8; ++e) acc[i][e] = 0.f;

  for (int i = 0; i < 64; ++i) {
    int h = l + (i << 6);
    float wv[8];
#pragma unroll
    for (int e = 0; e < 8; ++e) wv[e] = Wr[e * HD + h];
#pragma unroll
    for (int t4 = 0; t4 < 4; ++t4) {
      float rv = rh[(size_t)(tok0 + t4) * HD + h];
#pragma unroll
      for (int e = 0; e < 8; ++e) acc[t4][e] += rv * wv[e];
    }
  }
  // butterfly reduce across the 64-lane wave
#pragma unroll
  for (int off = 32; off >= 1; off >>= 1)
#pragma unroll
    for (int t4 = 0; t4 < 4; ++t4)
#pragma unroll
      for (int e = 0; e < 8; ++e)
        acc[t4][e] += __shfl_xor(acc[t4][e], off, 64);

  // lanes 0..3 each finalize one token (static indexing; no runtime reg-array index)
#pragma unroll
  for (int t4 = 0; t4 < 4; ++t4) {
    if (l == t4) {
      int tok = tok0 + t4;
      int bi = 0; float bv = acc[t4][0];
#pragma unroll
      for (int e = 1; e < 8; ++e) if (acc[t4][e] > bv) { bv = acc[t4][e]; bi = e; }
      int si = -1; float sv = -3.4e38f;
#pragma unroll
      for (int e = 0; e < 8; ++e) if (e != bi && acc[t4][e] > sv) { sv = acc[t4][e]; si = e; }
      float w0 = 1.f / (1.f + expf(sv - bv));  // softmax of [bv, sv]
      float w1 = 1.f - w0;
#pragma unroll
      for (int e = 0; e < 8; ++e) {
        logits[(size_t)tok * NE + e] = acc[t4][e];
        coef[tok * NE + e] = (e == bi) ? w0 : ((e == si) ? w1 : 0.f);
      }
    }
  }
}

// ---------------- K2: GEMM1  g = f2bf( 2*coef*gelu( x @ Bd^T ) ) ----------------
// M=8192 N=512 K=4096. Tile 128x128, BK=64, 512 threads (8 waves 2x4, wave=64x32).
// A (x) is f32 in global: reg-stage + convert + swizzled ds_write. B from Bd (bf16).
__global__ __launch_bounds__(512) void k2_gemm1(const float* __restrict__ x,
                                                const unsigned short* __restrict__ Bd,
                                                const float* __restrict__ coef,
                                                unsigned short* __restrict__ g) {
  __shared__ unsigned short smem[16384];  // A: bytes [0,16384), B: [16384,32768)
  char* lds = (char*)smem;
  const int t = threadIdx.x;
  const int l = t & 63, wave = t >> 6;
  const int wm = wave >> 2, wn = wave & 3;   // 2 x 4 wave grid
  const int m0 = blockIdx.y * 128;           // token tile
  const int n0 = blockIdx.x * 128;           // ea tile
  const int srow = t >> 2, scg = t & 3;      // staging: row 0..127, 16-elem col group
  const int swzw = (srow & 7) << 4;
  const int abyte = srow * 128 + scg * 32;
  const size_t xbase = (size_t)(m0 + srow) * HD + scg * 16;
  const size_t bbase = (size_t)(n0 + srow) * HD + scg * 16;

  f32x4 acc[4][2];
#pragma unroll
  for (int i = 0; i < 4; ++i)
#pragma unroll
    for (int j = 0; j < 2; ++j) acc[i][j] = (f32x4){0.f, 0.f, 0.f, 0.f};

  for (int k0 = 0; k0 < HD; k0 += 64) {
    const float4* xp = (const float4*)(x + xbase + k0);
    float4 v0 = xp[0], v1 = xp[1], v2 = xp[2], v3 = xp[3];
    short8 p0, p1;
    p0[0]=(short)f2bf(v0.x); p0[1]=(short)f2bf(v0.y); p0[2]=(short)f2bf(v0.z); p0[3]=(short)f2bf(v0.w);
    p0[4]=(short)f2bf(v1.x); p0[5]=(short)f2bf(v1.y); p0[6]=(short)f2bf(v1.z); p0[7]=(short)f2bf(v1.w);
    p1[0]=(short)f2bf(v2.x); p1[1]=(short)f2bf(v2.y); p1[2]=(short)f2bf(v2.z); p1[3]=(short)f2bf(v2.w);
    p1[4]=(short)f2bf(v3.x); p1[5]=(short)f2bf(v3.y); p1[6]=(short)f2bf(v3.z); p1[7]=(short)f2bf(v3.w);
    const short8* bp = (const short8*)(Bd + bbase + k0);
    short8 q0 = bp[0], q1 = bp[1];

    *(short8*)(lds + ((abyte     ) ^ swzw)) = p0;
    *(short8*)(lds + ((abyte + 16) ^ swzw)) = p1;
    *(short8*)(lds + 16384 + ((abyte     ) ^ swzw)) = q0;
    *(short8*)(lds + 16384 + ((abyte + 16) ^ swzw)) = q1;
    __syncthreads();

#pragma unroll
    for (int kk = 0; kk < 2; ++kk) {
      const int colb = kk * 64 + ((l >> 4) << 4);
      short8 af[4];
#pragma unroll
      for (int mi = 0; mi < 4; ++mi) {
        int row = wm * 64 + mi * 16 + (l & 15);
        af[mi] = *(const short8*)(lds + ((row * 128 + colb) ^ ((row & 7) << 4)));
      }
      short8 bf[2];
#pragma unroll
      for (int ni = 0; ni < 2; ++ni) {
        int row = wn * 32 + ni * 16 + (l & 15);
        bf[ni] = *(const short8*)(lds + 16384 + ((row * 128 + colb) ^ ((row & 7) << 4)));
      }
#pragma unroll
      for (int mi = 0; mi < 4; ++mi)
#pragma unroll
        for (int ni = 0; ni < 2; ++ni)
          acc[mi][ni] = __builtin_amdgcn_mfma_f32_16x16x32_bf16(af[mi], bf[ni], acc[mi][ni], 0, 0, 0);
    }
    __syncthreads();
  }

  // epilogue: g = bf16( 2*coef * gelu(acc) ); wave's 32-col span lies in ONE expert
  const int e_w = (n0 + wn * 32) >> 6;
#pragma unroll
  for (int mi = 0; mi < 4; ++mi) {
#pragma unroll
    for (int rr = 0; rr < 4; ++rr) {
      int token = m0 + wm * 64 + mi * 16 + ((l >> 4) << 2) + rr;
      float cf2 = 2.0f * coef[token * NE + e_w];
#pragma unroll
      for (int ni = 0; ni < 2; ++ni) {
        int col = n0 + wn * 32 + ni * 16 + (l & 15);
        float v = acc[mi][ni][rr];
        g[(size_t)token * EAD + col] = f2bf(cf2 * gelu_exact(v));
      }
    }
  }
}

// ---------------- K3: GEMM2  out = o + g @ Bu^T ----------------
// M=8192 N=4096 K=512. Tile 128x128, BK=64, 256 threads (4 waves 2x2, wave=64x64).
__global__ __launch_bounds__(256) void k3_gemm2(const unsigned short* __restrict__ g,
                                                const unsigned short* __restrict__ Bu,
                                                const float* __restrict__ o,
                                                float* __restrict__ out) {
  __shared__ unsigned short smem[16384];
  char* lds = (char*)smem;
  const int t = threadIdx.x;
  const int l = t & 63, wave = t >> 6;
  const int wm = wave >> 1, wn = wave & 1;   // 2 x 2
  const int m0 = blockIdx.y * 128;           // token tile
  const int n0 = blockIdx.x * 128;           // hcol tile
  const int srow = t >> 1, sh = t & 1;       // staging: row 0..127, 32-elem half
  const int swzw = (srow & 7) << 4;
  const int abyte = srow * 128 + sh * 64;
  const size_t gbase = (size_t)(m0 + srow) * EAD + sh * 32;
  const size_t bbase = (size_t)(n0 + srow) * EAD + sh * 32;

  f32x4 acc[4][4];
#pragma unroll
  for (int i = 0; i < 4; ++i)
#pragma unroll
    for (int j = 0; j < 4; ++j) acc[i][j] = (f32x4){0.f, 0.f, 0.f, 0.f};

  for (int k0 = 0; k0 < EAD; k0 += 64) {
    const short8* ap = (const short8*)(g + gbase + k0);
    short8 a0 = ap[0], a1 = ap[1], a2 = ap[2], a3 = ap[3];
    const short8* bp = (const short8*)(Bu + bbase + k0);
    short8 b0 = bp[0], b1 = bp[1], b2 = bp[2], b3 = bp[3];

    *(short8*)(lds + ((abyte     ) ^ swzw)) = a0;
    *(short8*)(lds + ((abyte + 16) ^ swzw)) = a1;
    *(short8*)(lds + ((abyte + 32) ^ swzw)) = a2;
    *(short8*)(lds + ((abyte + 48) ^ swzw)) = a3;
    *(short8*)(lds + 16384 + ((abyte     ) ^ swzw)) = b0;
    *(short8*)(lds + 16384 + ((abyte + 16) ^ swzw)) = b1;
    *(short8*)(lds + 16384 + ((abyte + 32) ^ swzw)) = b2;
    *(short8*)(lds + 16384 + ((abyte + 48) ^ swzw)) = b3;
    __syncthreads();

#pragma unroll
    for (int kk = 0; kk < 2; ++kk) {
      const int colb = kk * 64 + ((l >> 4) << 4);
      short8 af[4], bf[4];
#pragma unroll
      for (int mi = 0; mi < 4; ++mi) {
        int row = wm * 64 + mi * 16 + (l & 15);
        af[mi] = *(const short8*)(lds + ((row * 128 + colb) ^ ((row & 7) << 4)));
      }
#pragma unroll
      for (int ni = 0; ni < 4; ++ni) {
        int row = wn * 64 + ni * 16 + (l & 15);
        bf[ni] = *(const short8*)(lds + 16384 + ((row * 128 + colb) ^ ((row & 7) << 4)));
      }
#pragma unroll
      for (int mi = 0; mi < 4; ++mi)
#pragma unroll
        for (int ni = 0; ni < 4; ++ni)
          acc[mi][ni] = __builtin_amdgcn_mfma_f32_16x16x32_bf16(af[mi], bf[ni], acc[mi][ni], 0, 0, 0);
    }
    __syncthreads();
  }

#pragma unroll
  for (int mi = 0; mi < 4; ++mi)
#pragma unroll
    for (int ni = 0; ni < 4; ++ni)
#pragma unroll
      for (int rr = 0; rr < 4; ++rr) {
        int token = m0 + wm * 64 + mi * 16 + ((l >> 4) << 2) + rr;
        int col   = n0 + wn * 64 + ni * 16 + (l & 15);
        size_t idx = (size_t)token * HD + col;
        out[idx] = o[idx] + acc[mi][ni][rr];
      }
}

// ---------------- launch ----------------
extern "C" void kernel_launch(void* const* d_in, const int* in_sizes, int n_in,
                              void* d_out, int out_size, void* d_ws, size_t ws_size,
                              hipStream_t stream) {
  (void)in_sizes; (void)n_in; (void)out_size; (void)ws_size;
  const float* x  = (const float*)d_in[0];
  const float* o  = (const float*)d_in[1];
  const float* rh = (const float*)d_in[2];
  const float* Wr = (const float*)d_in[3];
  const float* Wd = (const float*)d_in[4];
  const float* Wu = (const float*)d_in[5];

  float* out    = (float*)d_out;
  float* logits = out + (size_t)NTOK * HD;   // second output, concatenated

  // workspace layout (bytes): coef[8192*8 f32] | g[8192*512 bf16] | Bd | Bu
  char* ws = (char*)d_ws;
  float*          coef = (float*)ws;                         // 262,144 B
  unsigned short* g    = (unsigned short*)(ws + 262144);     // 8,388,608 B
  unsigned short* Bd   = (unsigned short*)(ws + 8650752);    // 4,194,304 B
  unsigned short* Bu   = (unsigned short*)(ws + 12845056);   // 4,194,304 B

  k0_convert<<<16384, 256, 0, stream>>>(Wd, Wu, Bd, Bu);
  k1_router<<<512, 256, 0, stream>>>(rh, Wr, coef, logits);
  k2_gemm1<<<dim3(4, 64), 512, 0, stream>>>(x, Bd, coef, g);
  k3_gemm2<<<dim3(32, 64), 256, 0, stream>>>(g, Bu, o, out);
}